// Round 4
// baseline (295.187 us; speedup 1.0000x reference)
//
#include <hip/hip_runtime.h>
#include <hip/hip_bf16.h>

// TAttention: B=16, C=32, N=1024, T=128, R=10
//  K1 k_reduce_c : k[b,n,t] = sum_c alpha[c]*x[b,c,n,t]          (256 MB read)
//  K2 kw_partial2: p_w[b][r][ch][t] = sum_{n in ch} k*W_w        (8 MB read)
//  K2.5 kw_reduce: kwc[b][w][r][t] = sum_ch p_w                  (tiny)
//  K4 softmax_gemm: per (b,c,64n) block: recompute softmax(b) from kwc
//     (hidden under x loads), then out = att @ x via MFMA        (256R+256W)
// Floor ~784 MB -> ~112 us @ 7 TB/s.

#define B_ 16
#define C_ 32
#define N_ 1024
#define T_ 128
#define R_ 10

typedef __bf16 bf16x8 __attribute__((ext_vector_type(8)));
typedef __bf16 bf16x4 __attribute__((ext_vector_type(4)));
typedef float f32x4 __attribute__((ext_vector_type(4)));
typedef float f32x2 __attribute__((ext_vector_type(2)));

// ---------------------------------------------------------------- kernel 1
__global__ __launch_bounds__(256) void k_reduce_c(const float* __restrict__ x,
                                                  const float* __restrict__ alpha,
                                                  float* __restrict__ k) {
    int bid = blockIdx.x;            // B * N/8 = 2048
    int b   = bid >> 7;
    int nc  = bid & 127;
    int tid = threadIdx.x;
    int nl  = tid >> 5;
    int lc  = tid & 31;
    int n   = nc * 8 + nl;
    const float4* xb = reinterpret_cast<const float4*>(
        x + ((size_t)(b * C_) * N_ + n) * T_) + lc;
    float4 acc = {0.f, 0.f, 0.f, 0.f};
    #pragma unroll 8
    for (int c = 0; c < C_; ++c) {
        float a = alpha[c];
        float4 v = xb[(size_t)c * (N_ * T_ / 4)];
        acc.x += a * v.x; acc.y += a * v.y; acc.z += a * v.z; acc.w += a * v.w;
    }
    reinterpret_cast<float4*>(k + ((size_t)b * N_ + n) * T_)[lc] = acc;
}

// ---------------------------------------------------------------- kernel 2
// block=(b,ch of 32n): p_w[b][r][ch][t] = sum_{nl} k[b,n0+nl,t]*W_w[r,n0+nl]
__global__ __launch_bounds__(128) void kw_partial2(const float* __restrict__ k,
                                                   const float* __restrict__ W1,
                                                   const float* __restrict__ W2,
                                                   float* __restrict__ p1,
                                                   float* __restrict__ p2) {
    __shared__ float wl[32][20];
    int bid = blockIdx.x;            // b*32 + ch
    int b   = bid >> 5;
    int ch  = bid & 31;
    int n0  = ch * 32;
    int t   = threadIdx.x;
    for (int i = t; i < 32 * 20; i += 128) {
        int nl = i & 31, q = i >> 5;
        wl[nl][q] = (q < 10) ? W1[q * N_ + n0 + nl] : W2[(q - 10) * N_ + n0 + nl];
    }
    __syncthreads();
    float a1[R_] = {}, a2[R_] = {};
    const float* kb = k + ((size_t)b * N_ + n0) * T_ + t;
    #pragma unroll 2
    for (int g = 0; g < 4; ++g) {
        float kv[8];
        #pragma unroll
        for (int j = 0; j < 8; ++j) kv[j] = kb[(g * 8 + j) * T_];   // 8 in flight
        #pragma unroll
        for (int j = 0; j < 8; ++j) {
            int nl = g * 8 + j;
            #pragma unroll
            for (int r = 0; r < R_; ++r) {
                a1[r] += kv[j] * wl[nl][r];
                a2[r] += kv[j] * wl[nl][10 + r];
            }
        }
    }
    // coalesced per-r stores
    #pragma unroll
    for (int r = 0; r < R_; ++r) {
        size_t o = (((size_t)b * R_ + r) * 32 + ch) * T_ + t;
        p1[o] = a1[r];
        p2[o] = a2[r];
    }
}

// ---------------------------------------------------------------- kernel 2.5
// kwc[b][w][r][t] = sum_ch p_w[b][r][ch][t]
__global__ __launch_bounds__(128) void kw_reduce(const float* __restrict__ p1,
                                                 const float* __restrict__ p2,
                                                 float* __restrict__ kwc) {
    int bid = blockIdx.x;            // b*20 + w*10 + r
    int b = bid / 20;
    int q = bid - b * 20;
    int w = q / 10;
    int r = q - w * 10;
    int t = threadIdx.x;
    const float* src = (w ? p2 : p1) + (((size_t)b * R_ + r) * 32) * T_ + t;
    float s = 0.f;
    #pragma unroll
    for (int ch = 0; ch < 32; ++ch) s += src[ch * T_];
    kwc[(((size_t)b * 2 + w) * R_ + r) * T_ + t] = s;
}

// ---------------------------------------------------------------- kernel 4
// per (b,c,64n): x loads issued early; softmax(b) recomputed from kwc
// (hidden under loads); unnormalized e stored bf16 in attl; 1/sum applied
// in the f32 epilogue. MFMA core identical to the verified R2 kernel.
__global__ __launch_bounds__(256) void softmax_gemm(const float* __restrict__ x,
                                                    const float* __restrict__ kwc,
                                                    float* __restrict__ out) {
    __shared__ __align__(16) __bf16 attl[T_][T_];   // 32 KB swizzled e
    __shared__ __align__(16) __bf16 xsl[64][T_];    // 16 KB; first holds kws
    __shared__ float invs[T_];
    int bid = blockIdx.x;            // b*512 + c*16 + nc
    int nc  = bid & 15;
    int c   = (bid >> 4) & 31;
    int b   = bid >> 9;
    int tid = threadIdx.x;
    size_t slab = ((size_t)(b * C_ + c) * N_ + nc * 64) * T_;
    char*  attb = (char*)&attl[0][0];
    float* kws  = (float*)&xsl[0][0];               // [2][128][12] = 12 KB

    // kw loads FIRST (so the kws LDS-write waits only on these 10),
    // then the 8 x loads stay outstanding through the softmax.
    const float* kb = kwc + (size_t)b * 2560;
    float kwreg[10];
    #pragma unroll
    for (int i = 0; i < 10; ++i) kwreg[i] = kb[i * 256 + tid];
    const float4* gx = reinterpret_cast<const float4*>(x + slab);
    float4 xr[8];
    #pragma unroll
    for (int i = 0; i < 8; ++i) xr[i] = gx[i * 256 + tid];
    #pragma unroll
    for (int i = 0; i < 10; ++i) {
        int idx = i * 256 + tid;                    // w*1280 + r*128 + t
        int w   = idx >= 1280;
        int rem = idx - w * 1280;
        int r   = rem >> 7, t0 = rem & 127;
        kws[(w * 128 + t0) * 12 + r] = kwreg[i];
    }
    __syncthreads();

    // ---- softmax for row t = tid>>1 over s-half h = tid&1
    int t = tid >> 1, h = tid & 1;
    const float* w1r = &kws[t * 12];
    f32x4 m1a = *reinterpret_cast<const f32x4*>(w1r);
    f32x4 m1b = *reinterpret_cast<const f32x4*>(w1r + 4);
    f32x2 m1c = *reinterpret_cast<const f32x2*>(w1r + 8);
    const float* w2base = &kws[(128 + h * 64) * 12];
    float mx = -1e30f;
    #pragma unroll 4
    for (int j = 0; j < 64; ++j) {
        const float* w2 = w2base + j * 12;
        f32x4 qa = *reinterpret_cast<const f32x4*>(w2);
        f32x4 qb = *reinterpret_cast<const f32x4*>(w2 + 4);
        f32x2 qc = *reinterpret_cast<const f32x2*>(w2 + 8);
        float v = m1a[0]*qa[0]+m1a[1]*qa[1]+m1a[2]*qa[2]+m1a[3]*qa[3]
                + m1b[0]*qb[0]+m1b[1]*qb[1]+m1b[2]*qb[2]+m1b[3]*qb[3]
                + m1c[0]*qc[0]+m1c[1]*qc[1];
        mx = fmaxf(mx, v);
    }
    mx = fmaxf(mx, __shfl_xor(mx, 1));
    float sum = 0.f;
    int swzt = (t & 7) << 4;
    char* arow = attb + t * 256;
    #pragma unroll 4
    for (int j = 0; j < 32; ++j) {
        float v[2];
        #pragma unroll
        for (int u = 0; u < 2; ++u) {
            const float* w2 = w2base + (2 * j + u) * 12;
            f32x4 qa = *reinterpret_cast<const f32x4*>(w2);
            f32x4 qb = *reinterpret_cast<const f32x4*>(w2 + 4);
            f32x2 qc = *reinterpret_cast<const f32x2*>(w2 + 8);
            v[u] = m1a[0]*qa[0]+m1a[1]*qa[1]+m1a[2]*qa[2]+m1a[3]*qa[3]
                 + m1b[0]*qb[0]+m1b[1]*qb[1]+m1b[2]*qb[2]+m1b[3]*qb[3]
                 + m1c[0]*qc[0]+m1c[1]*qc[1];
        }
        float e0 = __expf(v[0] - mx), e1 = __expf(v[1] - mx);
        sum += e0 + e1;
        union { __bf16 hh[2]; unsigned u32; } cv;
        cv.hh[0] = (__bf16)e0; cv.hh[1] = (__bf16)e1;
        int bytec = (h * 128 + j * 4) ^ swzt;       // s pair at byte s*2
        *reinterpret_cast<unsigned*>(arow + bytec) = cv.u32;
    }
    sum += __shfl_xor(sum, 1);
    if (h == 0) invs[t] = 1.0f / sum;
    __syncthreads();                                 // kws reads done

    // ---- x regs -> xsl bf16 swizzled (overwrites kws region)
    char* xbb = (char*)&xsl[0][0];
    #pragma unroll
    for (int i = 0; i < 8; ++i) {
        int e = i * 256 + tid, row = e >> 5;
        bf16x4 hv = {(__bf16)xr[i].x, (__bf16)xr[i].y, (__bf16)xr[i].z, (__bf16)xr[i].w};
        *reinterpret_cast<bf16x4*>(xbb + row * 256 + (((e & 31) * 8) ^ ((row & 7) << 4))) = hv;
    }
    __syncthreads();

    // ---- MFMA core (verified R2 layout)
    int wave = tid >> 6, lane = tid & 63;
    int r16 = lane & 15, g = lane >> 4;
    int wt = wave & 1, wn = wave >> 1;
    int swz = (r16 & 7) << 4;
    f32x4 acc[2][4] = {};
    #pragma unroll
    for (int ks = 0; ks < 4; ++ks) {
        int kc = ks * 64 + g * 16;
        bf16x8 a[4], bx[2];
        #pragma unroll
        for (int tt = 0; tt < 4; ++tt)
            a[tt] = *reinterpret_cast<const bf16x8*>(
                attb + (wt * 64 + tt * 16 + r16) * 256 + (kc ^ swz));
        #pragma unroll
        for (int nn = 0; nn < 2; ++nn)
            bx[nn] = *reinterpret_cast<const bf16x8*>(
                xbb + (wn * 32 + nn * 16 + r16) * 256 + (kc ^ swz));
        #pragma unroll
        for (int nn = 0; nn < 2; ++nn)
            #pragma unroll
            for (int tt = 0; tt < 4; ++tt)
                acc[nn][tt] = __builtin_amdgcn_mfma_f32_16x16x32_bf16(
                    a[tt], bx[nn], acc[nn][tt], 0, 0, 0);
    }
    // ---- epilogue: scale by 1/sum (per t), float4 stores
    float* o = out + slab;
    #pragma unroll
    for (int nn = 0; nn < 2; ++nn) {
        int n_l = wn * 32 + nn * 16 + r16;
        #pragma unroll
        for (int tt = 0; tt < 4; ++tt) {
            int tb = wt * 64 + tt * 16 + g * 4;
            f32x4 iv = *reinterpret_cast<const f32x4*>(&invs[tb]);
            f32x4 vv = acc[nn][tt];
            vv[0] *= iv[0]; vv[1] *= iv[1]; vv[2] *= iv[2]; vv[3] *= iv[3];
            *reinterpret_cast<f32x4*>(o + (size_t)n_l * T_ + tb) = vv;
        }
    }
}

// ----------------------------------------------------------------
extern "C" void kernel_launch(void* const* d_in, const int* in_sizes, int n_in,
                              void* d_out, int out_size, void* d_ws, size_t ws_size,
                              hipStream_t stream) {
    const float* x     = (const float*)d_in[0];
    const float* W1    = (const float*)d_in[1];
    const float* W2    = (const float*)d_in[2];
    const float* alpha = (const float*)d_in[3];
    float* out = (float*)d_out;

    float* k   = (float*)d_ws;                          // 8 MB
    float* p1  = k  + (size_t)B_ * N_ * T_;             // [b][r][32][t] 2.62 MB
    float* p2  = p1 + (size_t)B_ * R_ * 32 * T_;
    float* kwc = p2 + (size_t)B_ * R_ * 32 * T_;        // [b][2][r][t] 160 KB

    k_reduce_c <<<dim3(B_ * (N_ / 8)), dim3(256), 0, stream>>>(x, alpha, k);
    kw_partial2<<<dim3(B_ * 32),       dim3(128), 0, stream>>>(k, W1, W2, p1, p2);
    kw_reduce  <<<dim3(B_ * 20),       dim3(128), 0, stream>>>(p1, p2, kwc);
    softmax_gemm<<<dim3(B_ * 512),     dim3(256), 0, stream>>>(x, kwc, out);
}

// Round 5
// 214.335 us; speedup vs baseline: 1.3772x; 1.3772x over previous
//
#include <hip/hip_runtime.h>
#include <hip/hip_bf16.h>

// TAttention: B=16, C=32, N=1024, T=128, R=10
//  K1 k_reduce_c : k[b,n,t] = sum_c alpha[c]*x[b,c,n,t]      (256 MB read, BW)
//  K2 kw_partial2: p_w[b][r][ch][t] partials                 (8 MB, fast)
//  K2.5 kw_reduce: kwc[b][w][r][t]                           (tiny)
//  K3 scores_softmax: att[b][t][s] bf16                      (tiny, 16 blocks)
//  K4 out_gemm2  : att in LDS (32 KB, swizzled); x B-frags DIRECT global->reg
//                  (no x LDS roundtrip); ks+1 prefetch; MFMA; f32x4 stores.
// R4 lesson: per-block softmax recompute = 145us of VALU. Never again.
// K4 target: ~394 MB actual HBM (x ~50% L3-hit) at >=4 TB/s -> ~95us.

#define B_ 16
#define C_ 32
#define N_ 1024
#define T_ 128
#define R_ 10

typedef __bf16 bf16x8 __attribute__((ext_vector_type(8)));
typedef __bf16 bf16x4 __attribute__((ext_vector_type(4)));
typedef float f32x4 __attribute__((ext_vector_type(4)));

// ---------------------------------------------------------------- kernel 1
__global__ __launch_bounds__(256) void k_reduce_c(const float* __restrict__ x,
                                                  const float* __restrict__ alpha,
                                                  float* __restrict__ k) {
    int bid = blockIdx.x;            // B * N/8 = 2048
    int b   = bid >> 7;
    int nc  = bid & 127;
    int tid = threadIdx.x;
    int nl  = tid >> 5;
    int lc  = tid & 31;
    int n   = nc * 8 + nl;
    const float4* xb = reinterpret_cast<const float4*>(
        x + ((size_t)(b * C_) * N_ + n) * T_) + lc;
    float4 acc = {0.f, 0.f, 0.f, 0.f};
    #pragma unroll 8
    for (int c = 0; c < C_; ++c) {
        float a = alpha[c];
        float4 v = xb[(size_t)c * (N_ * T_ / 4)];
        acc.x += a * v.x; acc.y += a * v.y; acc.z += a * v.z; acc.w += a * v.w;
    }
    reinterpret_cast<float4*>(k + ((size_t)b * N_ + n) * T_)[lc] = acc;
}

// ---------------------------------------------------------------- kernel 2
__global__ __launch_bounds__(128) void kw_partial2(const float* __restrict__ k,
                                                   const float* __restrict__ W1,
                                                   const float* __restrict__ W2,
                                                   float* __restrict__ p1,
                                                   float* __restrict__ p2) {
    __shared__ float wl[32][20];
    int bid = blockIdx.x;            // b*32 + ch
    int b   = bid >> 5;
    int ch  = bid & 31;
    int n0  = ch * 32;
    int t   = threadIdx.x;
    for (int i = t; i < 32 * 20; i += 128) {
        int nl = i & 31, q = i >> 5;
        wl[nl][q] = (q < 10) ? W1[q * N_ + n0 + nl] : W2[(q - 10) * N_ + n0 + nl];
    }
    __syncthreads();
    float a1[R_] = {}, a2[R_] = {};
    const float* kb = k + ((size_t)b * N_ + n0) * T_ + t;
    #pragma unroll 2
    for (int g = 0; g < 4; ++g) {
        float kv[8];
        #pragma unroll
        for (int j = 0; j < 8; ++j) kv[j] = kb[(g * 8 + j) * T_];
        #pragma unroll
        for (int j = 0; j < 8; ++j) {
            int nl = g * 8 + j;
            #pragma unroll
            for (int r = 0; r < R_; ++r) {
                a1[r] += kv[j] * wl[nl][r];
                a2[r] += kv[j] * wl[nl][10 + r];
            }
        }
    }
    #pragma unroll
    for (int r = 0; r < R_; ++r) {
        size_t o = (((size_t)b * R_ + r) * 32 + ch) * T_ + t;
        p1[o] = a1[r];
        p2[o] = a2[r];
    }
}

// ---------------------------------------------------------------- kernel 2.5
__global__ __launch_bounds__(128) void kw_reduce(const float* __restrict__ p1,
                                                 const float* __restrict__ p2,
                                                 float* __restrict__ kwc) {
    int bid = blockIdx.x;            // b*20 + w*10 + r
    int b = bid / 20;
    int q = bid - b * 20;
    int w = q / 10;
    int r = q - w * 10;
    int t = threadIdx.x;
    const float* src = (w ? p2 : p1) + (((size_t)b * R_ + r) * 32) * T_ + t;
    float s = 0.f;
    #pragma unroll
    for (int ch = 0; ch < 32; ++ch) s += src[ch * T_];
    kwc[(((size_t)b * 2 + w) * R_ + r) * T_ + t] = s;
}

// ---------------------------------------------------------------- kernel 3
// one block per b: scores + softmax -> att[b][t][s] bf16 (normalized)
__global__ __launch_bounds__(128) void scores_softmax(const float* __restrict__ kwc,
                                                      __bf16* __restrict__ att) {
    __shared__ __align__(16) float kw1s[T_][12];
    __shared__ __align__(16) float kw2s[T_][12];
    __shared__ float sc[T_][T_ + 1];
    int b = blockIdx.x;
    int t = threadIdx.x;
    const float* kb = kwc + (size_t)b * 2 * R_ * T_;
    #pragma unroll
    for (int r = 0; r < R_; ++r) {
        kw1s[t][r] = kb[r * T_ + t];
        kw2s[t][r] = kb[(R_ + r) * T_ + t];
    }
    __syncthreads();
    float myw[R_];
    #pragma unroll
    for (int r = 0; r < R_; ++r) myw[r] = kw1s[t][r];
    float mx = -1e30f;
    for (int s = 0; s < T_; ++s) {
        float wv[12];
        const float4* qr = reinterpret_cast<const float4*>(&kw2s[s][0]);
        #pragma unroll
        for (int q = 0; q < 3; ++q) *reinterpret_cast<float4*>(&wv[q * 4]) = qr[q];
        float v = 0.f;
        #pragma unroll
        for (int r = 0; r < R_; ++r) v += myw[r] * wv[r];
        sc[t][s] = v;
        mx = fmaxf(mx, v);
    }
    float sum = 0.f;
    for (int s = 0; s < T_; ++s) {
        float e = __expf(sc[t][s] - mx);
        sc[t][s] = e;
        sum += e;
    }
    float inv = 1.0f / sum;
    __bf16* arow = att + ((size_t)b * T_ + t) * T_;
    for (int s8 = 0; s8 < T_; s8 += 8) {
        bf16x8 hv;
        #pragma unroll
        for (int q = 0; q < 8; ++q) hv[q] = (__bf16)(sc[t][s8 + q] * inv);
        *reinterpret_cast<bf16x8*>(arow + s8) = hv;
    }
}

// ---------------------------------------------------------------- kernel 4
// per (b,c,64n): att LDS-staged (swizzled); x B-fragments straight from
// global (32 B contiguous per lane), ks+1 prefetched; verified MFMA/store map.
__global__ __launch_bounds__(256, 4) void out_gemm2(const float* __restrict__ x,
                                                    const __bf16* __restrict__ att,
                                                    float* __restrict__ out) {
    __shared__ __align__(16) __bf16 attl[T_][T_];   // 32 KB swizzled
    int bid = blockIdx.x;            // b*512 + c*16 + nc
    int nc  = bid & 15;
    int c   = (bid >> 4) & 31;
    int b   = bid >> 9;
    int tid = threadIdx.x;
    size_t slab = ((size_t)(b * C_ + c) * N_ + nc * 64) * T_;
    char* attb = (char*)&attl[0][0];

    const uint4* ga = reinterpret_cast<const uint4*>(att + (size_t)b * T_ * T_);
    #pragma unroll
    for (int i = 0; i < 8; ++i) {
        int e = i * 256 + tid, row = e >> 4;
        int bc = ((e & 15) * 16) ^ ((row & 7) << 4);
        *reinterpret_cast<uint4*>(attb + row * 256 + bc) = ga[e];
    }
    __syncthreads();

    int wave = tid >> 6, lane = tid & 63;
    int r16 = lane & 15, g = lane >> 4;
    int wt = wave & 1, wn = wave >> 1;
    int swz = (r16 & 7) << 4;

    // per-lane x rows (n) and 32B-contiguous k-slice cols (s = ks*32 + g*8)
    const float* xr0 = x + slab + (size_t)(wn * 32 + r16) * T_ + g * 8;
    const float* xr1 = xr0 + 16 * T_;

    f32x4 acc[2][4] = {};
    float4 c0a = *reinterpret_cast<const float4*>(xr0);
    float4 c0b = *reinterpret_cast<const float4*>(xr0 + 4);
    float4 c1a = *reinterpret_cast<const float4*>(xr1);
    float4 c1b = *reinterpret_cast<const float4*>(xr1 + 4);
    #pragma unroll
    for (int ks = 0; ks < 4; ++ks) {
        float4 n0a, n0b, n1a, n1b;
        if (ks < 3) {                // prefetch next k-slice
            int o = (ks + 1) * 32;
            n0a = *reinterpret_cast<const float4*>(xr0 + o);
            n0b = *reinterpret_cast<const float4*>(xr0 + o + 4);
            n1a = *reinterpret_cast<const float4*>(xr1 + o);
            n1b = *reinterpret_cast<const float4*>(xr1 + o + 4);
        }
        bf16x8 bx0 = {(__bf16)c0a.x, (__bf16)c0a.y, (__bf16)c0a.z, (__bf16)c0a.w,
                      (__bf16)c0b.x, (__bf16)c0b.y, (__bf16)c0b.z, (__bf16)c0b.w};
        bf16x8 bx1 = {(__bf16)c1a.x, (__bf16)c1a.y, (__bf16)c1a.z, (__bf16)c1a.w,
                      (__bf16)c1b.x, (__bf16)c1b.y, (__bf16)c1b.z, (__bf16)c1b.w};
        int kc = ks * 64 + g * 16;
        bf16x8 a[4];
        #pragma unroll
        for (int tt = 0; tt < 4; ++tt)
            a[tt] = *reinterpret_cast<const bf16x8*>(
                attb + (wt * 64 + tt * 16 + r16) * 256 + (kc ^ swz));
        #pragma unroll
        for (int tt = 0; tt < 4; ++tt)
            acc[0][tt] = __builtin_amdgcn_mfma_f32_16x16x32_bf16(a[tt], bx0, acc[0][tt], 0, 0, 0);
        #pragma unroll
        for (int tt = 0; tt < 4; ++tt)
            acc[1][tt] = __builtin_amdgcn_mfma_f32_16x16x32_bf16(a[tt], bx1, acc[1][tt], 0, 0, 0);
        c0a = n0a; c0b = n0b; c1a = n1a; c1b = n1b;
    }
    // D: col = lane&15 -> n, row = (lane>>4)*4+j -> t  => float4 along t
    float* o = out + slab;
    #pragma unroll
    for (int nn = 0; nn < 2; ++nn) {
        int n_l = wn * 32 + nn * 16 + r16;
        #pragma unroll
        for (int tt = 0; tt < 4; ++tt)
            *reinterpret_cast<f32x4*>(o + (size_t)n_l * T_ + (wt * 64 + tt * 16 + g * 4)) = acc[nn][tt];
    }
}

// ----------------------------------------------------------------
extern "C" void kernel_launch(void* const* d_in, const int* in_sizes, int n_in,
                              void* d_out, int out_size, void* d_ws, size_t ws_size,
                              hipStream_t stream) {
    const float* x     = (const float*)d_in[0];
    const float* W1    = (const float*)d_in[1];
    const float* W2    = (const float*)d_in[2];
    const float* alpha = (const float*)d_in[3];
    float* out = (float*)d_out;

    float* k    = (float*)d_ws;                         // 8 MB
    float* p1   = k   + (size_t)B_ * N_ * T_;           // [b][r][32][t]
    float* p2   = p1  + (size_t)B_ * R_ * 32 * T_;
    float* kwc  = p2  + (size_t)B_ * R_ * 32 * T_;      // [b][2][r][t]
    __bf16* att = (__bf16*)(kwc + (size_t)B_ * 2 * R_ * T_);  // [b][t][s]

    k_reduce_c   <<<dim3(B_ * (N_ / 8)), dim3(256), 0, stream>>>(x, alpha, k);
    kw_partial2  <<<dim3(B_ * 32),       dim3(128), 0, stream>>>(k, W1, W2, p1, p2);
    kw_reduce    <<<dim3(B_ * 20),       dim3(128), 0, stream>>>(p1, p2, kwc);
    scores_softmax<<<dim3(B_),           dim3(128), 0, stream>>>(kwc, att);
    out_gemm2    <<<dim3(B_ * 512),      dim3(256), 0, stream>>>(x, att, out);
}

// Round 6
// 186.174 us; speedup vs baseline: 1.5855x; 1.1513x over previous
//
#include <hip/hip_runtime.h>
#include <hip/hip_bf16.h>

// TAttention: B=16, C=32, N=1024, T=128, R=10
//  K1 k_reduce_c : k[b,n,t] = sum_c alpha[c]*x[b,c,n,t]      (256 MB read, BW)
//  K2 kw_partial2: p_w[b][r][ch][t] partials                 (8 MB, fast)
//  K2.5 kw_reduce: kwc[b][w][r][t]                           (tiny)
//  K3 scores_softmax: att[b][t][s] bf16                      (tiny, 16 blocks)
//  K4 out_gemm3  : block = (b,c,4 slabs). att staged once; x dbuf via REGS
//     (T14 issue-early/write-late, 128B/thread in flight); 48 KB LDS ->
//     3 blocks/CU; loads overlap MFMA+stores continuously.
// R5 lesson: fragment-direct loads = 2KB/CU in flight -> latency-bound.
// Keep bulk 16B-coalesced staging; overlap phases across slabs instead.

#define B_ 16
#define C_ 32
#define N_ 1024
#define T_ 128
#define R_ 10

typedef __bf16 bf16x8 __attribute__((ext_vector_type(8)));
typedef __bf16 bf16x4 __attribute__((ext_vector_type(4)));
typedef float f32x4 __attribute__((ext_vector_type(4)));

// ---------------------------------------------------------------- kernel 1
__global__ __launch_bounds__(256) void k_reduce_c(const float* __restrict__ x,
                                                  const float* __restrict__ alpha,
                                                  float* __restrict__ k) {
    int bid = blockIdx.x;            // B * N/8 = 2048
    int b   = bid >> 7;
    int nc  = bid & 127;
    int tid = threadIdx.x;
    int nl  = tid >> 5;
    int lc  = tid & 31;
    int n   = nc * 8 + nl;
    const float4* xb = reinterpret_cast<const float4*>(
        x + ((size_t)(b * C_) * N_ + n) * T_) + lc;
    float4 acc = {0.f, 0.f, 0.f, 0.f};
    #pragma unroll 8
    for (int c = 0; c < C_; ++c) {
        float a = alpha[c];
        float4 v = xb[(size_t)c * (N_ * T_ / 4)];
        acc.x += a * v.x; acc.y += a * v.y; acc.z += a * v.z; acc.w += a * v.w;
    }
    reinterpret_cast<float4*>(k + ((size_t)b * N_ + n) * T_)[lc] = acc;
}

// ---------------------------------------------------------------- kernel 2
__global__ __launch_bounds__(128) void kw_partial2(const float* __restrict__ k,
                                                   const float* __restrict__ W1,
                                                   const float* __restrict__ W2,
                                                   float* __restrict__ p1,
                                                   float* __restrict__ p2) {
    __shared__ float wl[32][20];
    int bid = blockIdx.x;            // b*32 + ch
    int b   = bid >> 5;
    int ch  = bid & 31;
    int n0  = ch * 32;
    int t   = threadIdx.x;
    for (int i = t; i < 32 * 20; i += 128) {
        int nl = i & 31, q = i >> 5;
        wl[nl][q] = (q < 10) ? W1[q * N_ + n0 + nl] : W2[(q - 10) * N_ + n0 + nl];
    }
    __syncthreads();
    float a1[R_] = {}, a2[R_] = {};
    const float* kb = k + ((size_t)b * N_ + n0) * T_ + t;
    #pragma unroll 2
    for (int g = 0; g < 4; ++g) {
        float kv[8];
        #pragma unroll
        for (int j = 0; j < 8; ++j) kv[j] = kb[(g * 8 + j) * T_];
        #pragma unroll
        for (int j = 0; j < 8; ++j) {
            int nl = g * 8 + j;
            #pragma unroll
            for (int r = 0; r < R_; ++r) {
                a1[r] += kv[j] * wl[nl][r];
                a2[r] += kv[j] * wl[nl][10 + r];
            }
        }
    }
    #pragma unroll
    for (int r = 0; r < R_; ++r) {
        size_t o = (((size_t)b * R_ + r) * 32 + ch) * T_ + t;
        p1[o] = a1[r];
        p2[o] = a2[r];
    }
}

// ---------------------------------------------------------------- kernel 2.5
__global__ __launch_bounds__(128) void kw_reduce(const float* __restrict__ p1,
                                                 const float* __restrict__ p2,
                                                 float* __restrict__ kwc) {
    int bid = blockIdx.x;            // b*20 + w*10 + r
    int b = bid / 20;
    int q = bid - b * 20;
    int w = q / 10;
    int r = q - w * 10;
    int t = threadIdx.x;
    const float* src = (w ? p2 : p1) + (((size_t)b * R_ + r) * 32) * T_ + t;
    float s = 0.f;
    #pragma unroll
    for (int ch = 0; ch < 32; ++ch) s += src[ch * T_];
    kwc[(((size_t)b * 2 + w) * R_ + r) * T_ + t] = s;
}

// ---------------------------------------------------------------- kernel 3
__global__ __launch_bounds__(128) void scores_softmax(const float* __restrict__ kwc,
                                                      __bf16* __restrict__ att) {
    __shared__ __align__(16) float kw1s[T_][12];
    __shared__ __align__(16) float kw2s[T_][12];
    __shared__ float sc[T_][T_ + 1];
    int b = blockIdx.x;
    int t = threadIdx.x;
    const float* kb = kwc + (size_t)b * 2 * R_ * T_;
    #pragma unroll
    for (int r = 0; r < R_; ++r) {
        kw1s[t][r] = kb[r * T_ + t];
        kw2s[t][r] = kb[(R_ + r) * T_ + t];
    }
    __syncthreads();
    float myw[R_];
    #pragma unroll
    for (int r = 0; r < R_; ++r) myw[r] = kw1s[t][r];
    float mx = -1e30f;
    for (int s = 0; s < T_; ++s) {
        float wv[12];
        const float4* qr = reinterpret_cast<const float4*>(&kw2s[s][0]);
        #pragma unroll
        for (int q = 0; q < 3; ++q) *reinterpret_cast<float4*>(&wv[q * 4]) = qr[q];
        float v = 0.f;
        #pragma unroll
        for (int r = 0; r < R_; ++r) v += myw[r] * wv[r];
        sc[t][s] = v;
        mx = fmaxf(mx, v);
    }
    float sum = 0.f;
    for (int s = 0; s < T_; ++s) {
        float e = __expf(sc[t][s] - mx);
        sc[t][s] = e;
        sum += e;
    }
    float inv = 1.0f / sum;
    __bf16* arow = att + ((size_t)b * T_ + t) * T_;
    for (int s8 = 0; s8 < T_; s8 += 8) {
        bf16x8 hv;
        #pragma unroll
        for (int q = 0; q < 8; ++q) hv[q] = (__bf16)(sc[t][s8 + q] * inv);
        *reinterpret_cast<bf16x8*>(arow + s8) = hv;
    }
}

// ---------------------------------------------------------------- kernel 4
// block = (b, c, slab-group of 4): att staged once (32KB swizzled); per slab:
// prefetch next slab to regs -> MFMA current from LDS -> store -> barrier ->
// regs->LDS -> barrier. 48 KB LDS, 3 blocks/CU.
__global__ __launch_bounds__(256, 3) void out_gemm3(const float* __restrict__ x,
                                                    const __bf16* __restrict__ att,
                                                    float* __restrict__ out) {
    __shared__ __align__(16) __bf16 attl[T_][T_];   // 32 KB swizzled
    __shared__ __align__(16) __bf16 xsl[64][T_];    // 16 KB swizzled
    int bid = blockIdx.x;            // b*128 + c*4 + sg
    int sg  = bid & 3;
    int c   = (bid >> 2) & 31;
    int b   = bid >> 7;
    int tid = threadIdx.x;
    char* attb = (char*)&attl[0][0];
    char* xbb  = (char*)&xsl[0][0];
    size_t slab0 = ((size_t)(b * C_ + c) * N_ + (sg * 4) * 64) * T_;

    // prologue: att (8 uint4) + slab0 x (8 float4) all issued back-to-back
    const uint4* ga = reinterpret_cast<const uint4*>(att + (size_t)b * T_ * T_);
    uint4 ar[8];
    #pragma unroll
    for (int i = 0; i < 8; ++i) ar[i] = ga[i * 256 + tid];
    const float4* gx0 = reinterpret_cast<const float4*>(x + slab0);
    float4 xr[8];
    #pragma unroll
    for (int j = 0; j < 8; ++j) xr[j] = gx0[j * 256 + tid];
    #pragma unroll
    for (int i = 0; i < 8; ++i) {
        int e = i * 256 + tid, row = e >> 4;
        int bc = ((e & 15) * 16) ^ ((row & 7) << 4);
        *reinterpret_cast<uint4*>(attb + row * 256 + bc) = ar[i];
    }
    #pragma unroll
    for (int j = 0; j < 8; ++j) {
        int e = j * 256 + tid, row = e >> 5;
        bf16x4 hv = {(__bf16)xr[j].x, (__bf16)xr[j].y, (__bf16)xr[j].z, (__bf16)xr[j].w};
        *reinterpret_cast<bf16x4*>(xbb + row * 256 + (((e & 31) * 8) ^ ((row & 7) << 4))) = hv;
    }
    __syncthreads();

    int wave = tid >> 6, lane = tid & 63;
    int r16 = lane & 15, g = lane >> 4;
    int wt = wave & 1, wn = wave >> 1;
    int swz = (r16 & 7) << 4;

    for (int i = 0; i < 4; ++i) {
        // T14 issue-early: next slab -> regs; in flight through MFMA+stores
        float4 xn[8];
        if (i < 3) {
            const float4* gxn = reinterpret_cast<const float4*>(
                x + slab0 + ((size_t)(i + 1) * 64) * T_);
            #pragma unroll
            for (int j = 0; j < 8; ++j) xn[j] = gxn[j * 256 + tid];
        }
        // MFMA on current slab (verified R2 core)
        f32x4 acc[2][4] = {};
        #pragma unroll
        for (int ks = 0; ks < 4; ++ks) {
            int kc = ks * 64 + g * 16;
            bf16x8 a[4], bx[2];
            #pragma unroll
            for (int tt = 0; tt < 4; ++tt)
                a[tt] = *reinterpret_cast<const bf16x8*>(
                    attb + (wt * 64 + tt * 16 + r16) * 256 + (kc ^ swz));
            #pragma unroll
            for (int nn = 0; nn < 2; ++nn)
                bx[nn] = *reinterpret_cast<const bf16x8*>(
                    xbb + (wn * 32 + nn * 16 + r16) * 256 + (kc ^ swz));
            #pragma unroll
            for (int nn = 0; nn < 2; ++nn)
                #pragma unroll
                for (int tt = 0; tt < 4; ++tt)
                    acc[nn][tt] = __builtin_amdgcn_mfma_f32_16x16x32_bf16(
                        a[tt], bx[nn], acc[nn][tt], 0, 0, 0);
        }
        // D: col = lane&15 -> n, row = (lane>>4)*4+j -> t  => float4 along t
        float* o = out + slab0 + ((size_t)i * 64) * T_;
        #pragma unroll
        for (int nn = 0; nn < 2; ++nn) {
            int n_l = wn * 32 + nn * 16 + r16;
            #pragma unroll
            for (int tt = 0; tt < 4; ++tt)
                *reinterpret_cast<f32x4*>(
                    o + (size_t)n_l * T_ + (wt * 64 + tt * 16 + g * 4)) = acc[nn][tt];
        }
        // write-late: regs -> LDS for next slab
        if (i < 3) {
            __syncthreads();                       // MFMA reads of xsl done
            #pragma unroll
            for (int j = 0; j < 8; ++j) {
                int e = j * 256 + tid, row = e >> 5;
                bf16x4 hv = {(__bf16)xn[j].x, (__bf16)xn[j].y,
                             (__bf16)xn[j].z, (__bf16)xn[j].w};
                *reinterpret_cast<bf16x4*>(
                    xbb + row * 256 + (((e & 31) * 8) ^ ((row & 7) << 4))) = hv;
            }
            __syncthreads();                       // xsl ready
        }
    }
}

// ----------------------------------------------------------------
extern "C" void kernel_launch(void* const* d_in, const int* in_sizes, int n_in,
                              void* d_out, int out_size, void* d_ws, size_t ws_size,
                              hipStream_t stream) {
    const float* x     = (const float*)d_in[0];
    const float* W1    = (const float*)d_in[1];
    const float* W2    = (const float*)d_in[2];
    const float* alpha = (const float*)d_in[3];
    float* out = (float*)d_out;

    float* k    = (float*)d_ws;                         // 8 MB
    float* p1   = k   + (size_t)B_ * N_ * T_;           // [b][r][32][t]
    float* p2   = p1  + (size_t)B_ * R_ * 32 * T_;
    float* kwc  = p2  + (size_t)B_ * R_ * 32 * T_;      // [b][2][r][t]
    __bf16* att = (__bf16*)(kwc + (size_t)B_ * 2 * R_ * T_);  // [b][t][s]

    k_reduce_c   <<<dim3(B_ * (N_ / 8)), dim3(256), 0, stream>>>(x, alpha, k);
    kw_partial2  <<<dim3(B_ * 32),       dim3(128), 0, stream>>>(k, W1, W2, p1, p2);
    kw_reduce    <<<dim3(B_ * 20),       dim3(128), 0, stream>>>(p1, p2, kwc);
    scores_softmax<<<dim3(B_),           dim3(128), 0, stream>>>(kwc, att);
    out_gemm3    <<<dim3(B_ * C_ * 4),   dim3(256), 0, stream>>>(x, att, out);
}

// Round 7
// 186.116 us; speedup vs baseline: 1.5860x; 1.0003x over previous
//
#include <hip/hip_runtime.h>
#include <hip/hip_bf16.h>

// TAttention: B=16, C=32, N=1024, T=128, R=10
//  K1 k_reduce_c : k[b,n,t] = sum_c alpha[c]*x[b,c,n,t]      (256 MB read, BW)
//  K2 kw_partial2: p_w[b][r][ch][t] partials                 (8 MB, fast)
//  K2.5 kw_reduce: kwc[b][w][r][t]                           (tiny)
//  K3 scores_softmax: att[b][t][s] bf16                      (tiny)
//  K4 out_gemm4  : block = (b,c,4 slabs); att once; x dbuf LDS (2x16KB);
//     RAW s_barrier (no vmcnt drain!) + lgkmcnt(0) only; loads counted-waited
//     by compiler-exact vmcnt; stores drain in background. (R6 lesson:
//     __syncthreads = vmcnt(0) drain killed all cross-slab overlap.)

#define B_ 16
#define C_ 32
#define N_ 1024
#define T_ 128
#define R_ 10

typedef __bf16 bf16x8 __attribute__((ext_vector_type(8)));
typedef __bf16 bf16x4 __attribute__((ext_vector_type(4)));
typedef float f32x4 __attribute__((ext_vector_type(4)));

// LDS fence-barrier: waits local writes, hard workgroup barrier, compiler
// memory fences both sides, NO vmcnt drain (stores/loads keep flying).
__device__ __forceinline__ void lds_barrier() {
    asm volatile("s_waitcnt lgkmcnt(0)" ::: "memory");
    __builtin_amdgcn_s_barrier();
    asm volatile("" ::: "memory");
}

// ---------------------------------------------------------------- kernel 1
__global__ __launch_bounds__(256) void k_reduce_c(const float* __restrict__ x,
                                                  const float* __restrict__ alpha,
                                                  float* __restrict__ k) {
    int bid = blockIdx.x;            // B * N/8 = 2048
    int b   = bid >> 7;
    int nc  = bid & 127;
    int tid = threadIdx.x;
    int nl  = tid >> 5;
    int lc  = tid & 31;
    int n   = nc * 8 + nl;
    const float4* xb = reinterpret_cast<const float4*>(
        x + ((size_t)(b * C_) * N_ + n) * T_) + lc;
    float4 acc = {0.f, 0.f, 0.f, 0.f};
    #pragma unroll 8
    for (int c = 0; c < C_; ++c) {
        float a = alpha[c];
        float4 v = xb[(size_t)c * (N_ * T_ / 4)];
        acc.x += a * v.x; acc.y += a * v.y; acc.z += a * v.z; acc.w += a * v.w;
    }
    reinterpret_cast<float4*>(k + ((size_t)b * N_ + n) * T_)[lc] = acc;
}

// ---------------------------------------------------------------- kernel 2
__global__ __launch_bounds__(128) void kw_partial2(const float* __restrict__ k,
                                                   const float* __restrict__ W1,
                                                   const float* __restrict__ W2,
                                                   float* __restrict__ p1,
                                                   float* __restrict__ p2) {
    __shared__ float wl[32][20];
    int bid = blockIdx.x;            // b*32 + ch
    int b   = bid >> 5;
    int ch  = bid & 31;
    int n0  = ch * 32;
    int t   = threadIdx.x;
    for (int i = t; i < 32 * 20; i += 128) {
        int nl = i & 31, q = i >> 5;
        wl[nl][q] = (q < 10) ? W1[q * N_ + n0 + nl] : W2[(q - 10) * N_ + n0 + nl];
    }
    __syncthreads();
    float a1[R_] = {}, a2[R_] = {};
    const float* kb = k + ((size_t)b * N_ + n0) * T_ + t;
    #pragma unroll 2
    for (int g = 0; g < 4; ++g) {
        float kv[8];
        #pragma unroll
        for (int j = 0; j < 8; ++j) kv[j] = kb[(g * 8 + j) * T_];
        #pragma unroll
        for (int j = 0; j < 8; ++j) {
            int nl = g * 8 + j;
            #pragma unroll
            for (int r = 0; r < R_; ++r) {
                a1[r] += kv[j] * wl[nl][r];
                a2[r] += kv[j] * wl[nl][10 + r];
            }
        }
    }
    #pragma unroll
    for (int r = 0; r < R_; ++r) {
        size_t o = (((size_t)b * R_ + r) * 32 + ch) * T_ + t;
        p1[o] = a1[r];
        p2[o] = a2[r];
    }
}

// ---------------------------------------------------------------- kernel 2.5
__global__ __launch_bounds__(128) void kw_reduce(const float* __restrict__ p1,
                                                 const float* __restrict__ p2,
                                                 float* __restrict__ kwc) {
    int bid = blockIdx.x;            // b*20 + w*10 + r
    int b = bid / 20;
    int q = bid - b * 20;
    int w = q / 10;
    int r = q - w * 10;
    int t = threadIdx.x;
    const float* src = (w ? p2 : p1) + (((size_t)b * R_ + r) * 32) * T_ + t;
    float s = 0.f;
    #pragma unroll
    for (int ch = 0; ch < 32; ++ch) s += src[ch * T_];
    kwc[(((size_t)b * 2 + w) * R_ + r) * T_ + t] = s;
}

// ---------------------------------------------------------------- kernel 3
__global__ __launch_bounds__(128) void scores_softmax(const float* __restrict__ kwc,
                                                      __bf16* __restrict__ att) {
    __shared__ __align__(16) float kw1s[T_][12];
    __shared__ __align__(16) float kw2s[T_][12];
    __shared__ float sc[T_][T_ + 1];
    int b = blockIdx.x;
    int t = threadIdx.x;
    const float* kb = kwc + (size_t)b * 2 * R_ * T_;
    #pragma unroll
    for (int r = 0; r < R_; ++r) {
        kw1s[t][r] = kb[r * T_ + t];
        kw2s[t][r] = kb[(R_ + r) * T_ + t];
    }
    __syncthreads();
    float myw[R_];
    #pragma unroll
    for (int r = 0; r < R_; ++r) myw[r] = kw1s[t][r];
    float mx = -1e30f;
    for (int s = 0; s < T_; ++s) {
        float wv[12];
        const float4* qr = reinterpret_cast<const float4*>(&kw2s[s][0]);
        #pragma unroll
        for (int q = 0; q < 3; ++q) *reinterpret_cast<float4*>(&wv[q * 4]) = qr[q];
        float v = 0.f;
        #pragma unroll
        for (int r = 0; r < R_; ++r) v += myw[r] * wv[r];
        sc[t][s] = v;
        mx = fmaxf(mx, v);
    }
    float sum = 0.f;
    for (int s = 0; s < T_; ++s) {
        float e = __expf(sc[t][s] - mx);
        sc[t][s] = e;
        sum += e;
    }
    float inv = 1.0f / sum;
    __bf16* arow = att + ((size_t)b * T_ + t) * T_;
    for (int s8 = 0; s8 < T_; s8 += 8) {
        bf16x8 hv;
        #pragma unroll
        for (int q = 0; q < 8; ++q) hv[q] = (__bf16)(sc[t][s8 + q] * inv);
        *reinterpret_cast<bf16x8*>(arow + s8) = hv;
    }
}

// ---------------------------------------------------------------- kernel 4
// block = (b, c, 4 slabs); att staged once (32 KB swizzled); x double-buffered
// (2x16 KB). One raw lds_barrier per slab. Stores never waited on.
__global__ __launch_bounds__(256, 2) void out_gemm4(const float* __restrict__ x,
                                                    const __bf16* __restrict__ att,
                                                    float* __restrict__ out) {
    __shared__ __align__(16) __bf16 attl[T_][T_];      // 32 KB swizzled
    __shared__ __align__(16) __bf16 xsl[2][64][T_];    // 2 x 16 KB swizzled
    int bid = blockIdx.x;            // b*128 + c*4 + sg
    int sg  = bid & 3;
    int c   = (bid >> 2) & 31;
    int b   = bid >> 7;
    int tid = threadIdx.x;
    char* attb = (char*)&attl[0][0];
    size_t slab0 = ((size_t)(b * C_ + c) * N_ + (sg * 4) * 64) * T_;

    // ---- prologue: att + slab0, staged, one barrier
    const uint4* ga = reinterpret_cast<const uint4*>(att + (size_t)b * T_ * T_);
    uint4 ar[8];
    #pragma unroll
    for (int i = 0; i < 8; ++i) ar[i] = ga[i * 256 + tid];
    const float4* gx0 = reinterpret_cast<const float4*>(x + slab0);
    float4 xr[8];
    #pragma unroll
    for (int j = 0; j < 8; ++j) xr[j] = gx0[j * 256 + tid];
    #pragma unroll
    for (int i = 0; i < 8; ++i) {
        int e = i * 256 + tid, row = e >> 4;
        int bc = ((e & 15) * 16) ^ ((row & 7) << 4);
        *reinterpret_cast<uint4*>(attb + row * 256 + bc) = ar[i];
    }
    {
        char* xb0 = (char*)&xsl[0][0][0];
        #pragma unroll
        for (int j = 0; j < 8; ++j) {
            int e = j * 256 + tid, row = e >> 5;
            bf16x4 hv = {(__bf16)xr[j].x, (__bf16)xr[j].y, (__bf16)xr[j].z, (__bf16)xr[j].w};
            *reinterpret_cast<bf16x4*>(xb0 + row * 256 + (((e & 31) * 8) ^ ((row & 7) << 4))) = hv;
        }
    }
    lds_barrier();

    int wave = tid >> 6, lane = tid & 63;
    int r16 = lane & 15, g = lane >> 4;
    int wt = wave & 1, wn = wave >> 1;
    int swz = (r16 & 7) << 4;

    #pragma unroll
    for (int i = 0; i < 4; ++i) {
        // issue next-slab loads (in flight through MFMA+stores; compiler
        // emits counted vmcnt before the ds_writes below — never 0)
        float4 xn[8];
        if (i < 3) {
            const float4* gxn = reinterpret_cast<const float4*>(
                x + slab0 + ((size_t)(i + 1) * 64) * T_);
            #pragma unroll
            for (int j = 0; j < 8; ++j) xn[j] = gxn[j * 256 + tid];
        }
        // MFMA on current slab from buf i&1 (verified R2 core)
        const char* xbb = (const char*)&xsl[i & 1][0][0];
        f32x4 acc[2][4] = {};
        #pragma unroll
        for (int ks = 0; ks < 4; ++ks) {
            int kc = ks * 64 + g * 16;
            bf16x8 a[4], bx[2];
            #pragma unroll
            for (int tt = 0; tt < 4; ++tt)
                a[tt] = *reinterpret_cast<const bf16x8*>(
                    attb + (wt * 64 + tt * 16 + r16) * 256 + (kc ^ swz));
            #pragma unroll
            for (int nn = 0; nn < 2; ++nn)
                bx[nn] = *reinterpret_cast<const bf16x8*>(
                    xbb + (wn * 32 + nn * 16 + r16) * 256 + (kc ^ swz));
            #pragma unroll
            for (int nn = 0; nn < 2; ++nn)
                #pragma unroll
                for (int tt = 0; tt < 4; ++tt)
                    acc[nn][tt] = __builtin_amdgcn_mfma_f32_16x16x32_bf16(
                        a[tt], bx[nn], acc[nn][tt], 0, 0, 0);
        }
        // stores (background drain; nothing ever waits vmcnt(0) on them)
        float* o = out + slab0 + ((size_t)i * 64) * T_;
        #pragma unroll
        for (int nn = 0; nn < 2; ++nn) {
            int n_l = wn * 32 + nn * 16 + r16;
            #pragma unroll
            for (int tt = 0; tt < 4; ++tt)
                *reinterpret_cast<f32x4*>(
                    o + (size_t)n_l * T_ + (wt * 64 + tt * 16 + g * 4)) = acc[nn][tt];
        }
        // write next slab into the other buffer; one barrier per slab.
        // Race-free: buf p^1 was last read at MFMA(i-1), before barrier(i-1).
        if (i < 3) {
            char* xw = (char*)&xsl[(i + 1) & 1][0][0];
            #pragma unroll
            for (int j = 0; j < 8; ++j) {
                int e = j * 256 + tid, row = e >> 5;
                bf16x4 hv = {(__bf16)xn[j].x, (__bf16)xn[j].y,
                             (__bf16)xn[j].z, (__bf16)xn[j].w};
                *reinterpret_cast<bf16x4*>(
                    xw + row * 256 + (((e & 31) * 8) ^ ((row & 7) << 4))) = hv;
            }
            lds_barrier();
        }
    }
}

// ----------------------------------------------------------------
extern "C" void kernel_launch(void* const* d_in, const int* in_sizes, int n_in,
                              void* d_out, int out_size, void* d_ws, size_t ws_size,
                              hipStream_t stream) {
    const float* x     = (const float*)d_in[0];
    const float* W1    = (const float*)d_in[1];
    const float* W2    = (const float*)d_in[2];
    const float* alpha = (const float*)d_in[3];
    float* out = (float*)d_out;

    float* k    = (float*)d_ws;                         // 8 MB
    float* p1   = k   + (size_t)B_ * N_ * T_;           // [b][r][32][t]
    float* p2   = p1  + (size_t)B_ * R_ * 32 * T_;
    float* kwc  = p2  + (size_t)B_ * R_ * 32 * T_;      // [b][2][r][t]
    __bf16* att = (__bf16*)(kwc + (size_t)B_ * 2 * R_ * T_);  // [b][t][s]

    k_reduce_c   <<<dim3(B_ * (N_ / 8)), dim3(256), 0, stream>>>(x, alpha, k);
    kw_partial2  <<<dim3(B_ * 32),       dim3(128), 0, stream>>>(k, W1, W2, p1, p2);
    kw_reduce    <<<dim3(B_ * 20),       dim3(128), 0, stream>>>(p1, p2, kwc);
    scores_softmax<<<dim3(B_),           dim3(128), 0, stream>>>(kwc, att);
    out_gemm4    <<<dim3(B_ * C_ * 4),   dim3(256), 0, stream>>>(x, att, out);
}